// Round 1
// baseline (270.133 us; speedup 1.0000x reference)
//
#include <hip/hip_runtime.h>

#define Hdim 512
#define Wdim 512
#define Cdim 256
#define OUTH 7
#define OUTW 7
#define SW 513   // padded widths of integral image S: [H+1][W+1][C]
#define SH 513
#define NROI_BINS (OUTH * OUTW)

static constexpr size_t S_ELEMS = (size_t)SH * SW * Cdim;        // 67,371,264
static constexpr size_t S_BYTES = S_ELEMS * sizeof(float);       // ~257 MB

// ---------------- Kernel A: cumsum along H (rows), f64 accumulate ----------
// grid: Wdim blocks x Cdim threads. Thread (w = blockIdx, c = threadIdx)
// walks h = 0..511, writing S[h+1][w+1][c]. Also zeroes pad row 0 and col 0.
__global__ void colcum_kernel(const float* __restrict__ x, float* __restrict__ S) {
    const int w = blockIdx.x;       // 0..511
    const int c = threadIdx.x;      // 0..255
    const int t = w * Cdim + c;     // 0..131071

    // zero pad row 0: SW*C = 131,328 elements, stride = thread count 131,072
    for (size_t idx = t; idx < (size_t)SW * Cdim; idx += (size_t)Wdim * Cdim)
        S[idx] = 0.0f;

    const float* xp = x + (size_t)w * Cdim + c;
    float* sp = S + (size_t)SW * Cdim + (size_t)(w + 1) * Cdim + c;  // row 1, col w+1
    float* zp = S + (size_t)SW * Cdim + c;                           // row 1, col 0

    double acc = 0.0;
    for (int h0 = 0; h0 < Hdim; h0 += 8) {
        float v[8];
        #pragma unroll
        for (int k = 0; k < 8; ++k)
            v[k] = xp[(size_t)(h0 + k) * (Wdim * Cdim)];
        #pragma unroll
        for (int k = 0; k < 8; ++k) {
            acc += (double)v[k];
            sp[(size_t)(h0 + k) * (SW * Cdim)] = (float)acc;
        }
        if (w == 0) {   // uniform per block (w == blockIdx)
            #pragma unroll
            for (int k = 0; k < 8; ++k)
                zp[(size_t)(h0 + k) * (SW * Cdim)] = 0.0f;
        }
    }
}

// ---------------- Kernel B: cumsum along W (cols), in place, f64 accumulate -
// grid: Hdim blocks x Cdim threads. Thread (h = blockIdx+1, c) walks w=1..512.
__global__ void rowcum_kernel(float* __restrict__ S) {
    const int h = blockIdx.x + 1;   // 1..512
    const int c = threadIdx.x;
    float* sp = S + (size_t)h * (SW * Cdim) + c;  // col 0 of row h

    double acc = 0.0;
    for (int w0 = 1; w0 <= Wdim; w0 += 8) {
        float v[8];
        #pragma unroll
        for (int k = 0; k < 8; ++k)
            v[k] = sp[(size_t)(w0 + k) * Cdim];
        #pragma unroll
        for (int k = 0; k < 8; ++k) {
            acc += (double)v[k];
            sp[(size_t)(w0 + k) * Cdim] = (float)acc;
        }
    }
}

// ---------------- shared bin-edge math (replicates reference exactly) ------
__device__ __forceinline__ void roi_bounds(const float4 r, int& hs, int& ws,
                                           int& rh, int& rw) {
    hs = (int)floorf((float)Hdim * r.x);
    ws = (int)floorf((float)Wdim * r.y);
    int he = (int)floorf((float)Hdim * r.z);
    int we = (int)floorf((float)Wdim * r.w);
    he = max(he, hs + 1);
    we = max(we, ws + 1);
    rh = he - hs;
    rw = we - ws;
}

// ---------------- Kernel C: gather 4 corners per bin ------------------------
// grid: (N * OUTH) blocks x Cdim threads. Block = (roi n, out-row i).
__global__ void gather_kernel(const float* __restrict__ S,
                              const float* __restrict__ rois,
                              float* __restrict__ out, int N) {
    const int n = blockIdx.x / OUTH;
    const int i = blockIdx.x % OUTH;
    const int c = threadIdx.x;
    if (n >= N) return;

    const float4 r = reinterpret_cast<const float4*>(rois)[n];  // y0,x0,y1,x1
    int hs, ws, rh, rw;
    roi_bounds(r, hs, ws, rh, rw);

    const int hb0 = hs + (i * rh) / OUTH;
    const int hb1 = hs + ((i + 1) * rh + OUTH - 1) / OUTH;   // ceil div
    const float dh = (float)(hb1 - hb0);

    const float* S0 = S + (size_t)hb0 * (SW * Cdim) + c;
    const float* S1 = S + (size_t)hb1 * (SW * Cdim) + c;
    float* op = out + ((size_t)(n * OUTH + i) * OUTW) * Cdim + c;

    #pragma unroll
    for (int j = 0; j < OUTW; ++j) {
        const int wb0 = ws + (j * rw) / OUTW;
        const int wb1 = ws + ((j + 1) * rw + OUTW - 1) / OUTW;
        const float s11 = S1[(size_t)wb1 * Cdim];
        const float s01 = S0[(size_t)wb1 * Cdim];
        const float s10 = S1[(size_t)wb0 * Cdim];
        const float s00 = S0[(size_t)wb0 * Cdim];
        const float area = dh * (float)(wb1 - wb0);
        op[(size_t)j * Cdim] = (((s11 - s01) - s10) + s00) / area;
    }
}

// ---------------- Fallback: direct per-bin summation (ws too small) --------
__global__ void direct_kernel(const float* __restrict__ x,
                              const float* __restrict__ rois,
                              float* __restrict__ out, int N) {
    const int bid = blockIdx.x;                 // n*49 + i*7 + j
    const int n = bid / NROI_BINS;
    const int rem = bid % NROI_BINS;
    const int i = rem / OUTW;
    const int j = rem % OUTW;
    const int c = threadIdx.x;
    if (n >= N) return;

    const float4 r = reinterpret_cast<const float4*>(rois)[n];
    int hs, ws, rh, rw;
    roi_bounds(r, hs, ws, rh, rw);

    const int hb0 = hs + (i * rh) / OUTH;
    const int hb1 = hs + ((i + 1) * rh + OUTH - 1) / OUTH;
    const int wb0 = ws + (j * rw) / OUTW;
    const int wb1 = ws + ((j + 1) * rw + OUTW - 1) / OUTW;

    double acc = 0.0;
    for (int h = hb0; h < hb1; ++h) {
        const float* xp = x + ((size_t)h * Wdim) * Cdim + c;
        for (int w = wb0; w < wb1; ++w)
            acc += (double)xp[(size_t)w * Cdim];
    }
    const float area = (float)((hb1 - hb0) * (wb1 - wb0));
    out[((size_t)bid) * Cdim + c] = (float)(acc / (double)area);
}

extern "C" void kernel_launch(void* const* d_in, const int* in_sizes, int n_in,
                              void* d_out, int out_size, void* d_ws, size_t ws_size,
                              hipStream_t stream) {
    const float* x    = (const float*)d_in[0];
    const float* rois = (const float*)d_in[1];
    float* out        = (float*)d_out;
    const int N       = in_sizes[1] / 4;   // 2000

    if (ws_size >= S_BYTES) {
        float* S = (float*)d_ws;
        colcum_kernel<<<Wdim, Cdim, 0, stream>>>(x, S);
        rowcum_kernel<<<Hdim, Cdim, 0, stream>>>(S);
        gather_kernel<<<N * OUTH, Cdim, 0, stream>>>(S, rois, out, N);
    } else {
        direct_kernel<<<N * NROI_BINS, Cdim, 0, stream>>>(x, rois, out, N);
    }
}